// Round 3
// baseline (373.788 us; speedup 1.0000x reference)
//
#include <hip/hip_runtime.h>
#include <hip/hip_bf16.h>

typedef __attribute__((ext_vector_type(8))) short short8;
typedef __attribute__((ext_vector_type(4))) float f32x4;

#define MFMA16(a, b, c) __builtin_amdgcn_mfma_f32_16x16x32_bf16((a), (b), (c), 0, 0, 0)

constexpr int Bc = 2, Lc = 2048, Hc = 16, Ec = 64;
constexpr int QBLK = 64;
constexpr float SCALE = 0.125f;               // 1/sqrt(64), exact in bf16
constexpr float LOG2E = 1.4426950408889634f;
constexpr float NEGBIG = -3.0e38f;

union SW { short8 s8; unsigned u[4]; float4 f4; };

__device__ __forceinline__ unsigned cvtpk(float lo, float hi) {
  unsigned r;
  asm("v_cvt_pk_bf16_f32 %0, %1, %2" : "=v"(r) : "v"(lo), "v"(hi));
  return r;
}

// 16-lane max reduction step on the VALU pipe (DPP).
template <int CTRL>
__device__ __forceinline__ float dppmax(float x) {
  int xi = __builtin_bit_cast(int, x);
  int yi = __builtin_amdgcn_update_dpp(xi, xi, CTRL, 0xF, 0xF, false);
  return fmaxf(x, __builtin_bit_cast(float, yi));
}

__global__ __launch_bounds__(512, 8)
void attn_fwd(const float* __restrict__ Qg, const float* __restrict__ Kg,
              const float* __restrict__ Vg, float* __restrict__ Og) {
  // smem (shorts):
  //  [0,8192):      kt dbuf: [64 s][64 e] bf16, idx ^ ((row&7)<<3)
  //  [8192,16384):  vt dbuf: [64 e][64 s] bf16, s-chunk slot = chunk ^ (e&7)
  //  [16384,20480): pt per wave [16][32], k-chunk slot = chunk ^ (q16>>2)
  // merge scratch (floats, after final barrier): acc 4096 + m 64 + l 64
  __shared__ __align__(16) short smem[20480];

  const int nqb = Lc / QBLK;                 // 32
  const int bid = blockIdx.x;
  const int qblk = (nqb - 1) - (bid % nqb);  // heavy blocks first
  const int h = (bid / nqb) % Hc;
  const int b = bid / (nqb * Hc);
  const int Qb = qblk * QBLK;

  const int t = threadIdx.x;
  const int w = t >> 6;        // 0..7
  const int qsub = w & 3;      // q sub-block
  const int par = w >> 2;      // s parity (0: rows 0-31 of round, 1: rows 32-63)
  const int l = t & 63;
  const int n = l & 15;
  const int g = l >> 4;

  short* pt = smem + 16384 + w * 512;

  // ---- Q fragments (A-layout: row=n, k=g*8+j), scale folded in ----
  short8 qf[2];
  {
    const int q = Qb + qsub * 16 + n;
    const float* qp = Qg + ((size_t)(b * Lc + q) * Hc + h) * Ec + g * 8;
    SW a0, a1;
    a0.f4 = reinterpret_cast<const float4*>(qp)[0];
    a1.f4 = reinterpret_cast<const float4*>(qp)[1];
    SW b0, b1;
    b0.f4 = reinterpret_cast<const float4*>(qp + 32)[0];
    b1.f4 = reinterpret_cast<const float4*>(qp + 32)[1];
    SW r0, r1;
    r0.u[0] = cvtpk(a0.f4.x * SCALE, a0.f4.y * SCALE);
    r0.u[1] = cvtpk(a0.f4.z * SCALE, a0.f4.w * SCALE);
    r0.u[2] = cvtpk(a1.f4.x * SCALE, a1.f4.y * SCALE);
    r0.u[3] = cvtpk(a1.f4.z * SCALE, a1.f4.w * SCALE);
    r1.u[0] = cvtpk(b0.f4.x * SCALE, b0.f4.y * SCALE);
    r1.u[1] = cvtpk(b0.f4.z * SCALE, b0.f4.w * SCALE);
    r1.u[2] = cvtpk(b1.f4.x * SCALE, b1.f4.y * SCALE);
    r1.u[3] = cvtpk(b1.f4.z * SCALE, b1.f4.w * SCALE);
    qf[0] = r0.s8;
    qf[1] = r1.s8;
  }

  short8 onesv;
  #pragma unroll
  for (int j = 0; j < 8; ++j) onesv[j] = (short)0x3F80;  // bf16 1.0
  const f32x4 zero4 = {0.f, 0.f, 0.f, 0.f};

  f32x4 acc[4] = {zero4, zero4, zero4, zero4};
  float mrun[4] = {NEGBIG, NEGBIG, NEGBIG, NEGBIG};
  float lrun[4] = {0.f, 0.f, 0.f, 0.f};

  // staging coordinates: 512 threads stage 64 rows of K and V^T per round
  const int srow = t >> 3, sc8 = (t & 7) * 8;  // K: row 0..63, 8 cols
  const int ve = l, vs0 = w * 8;               // V^T: col e = lane, 8 s rows

  float4 ka, kb;
  float va[8];

  auto issue = [&](int r0) {
    const float* kp = Kg + ((size_t)(b * Lc + r0 + srow) * Hc + h) * Ec + sc8;
    ka = reinterpret_cast<const float4*>(kp)[0];
    kb = reinterpret_cast<const float4*>(kp)[1];
    const float* vp = Vg + ((size_t)(b * Lc + r0 + vs0) * Hc + h) * Ec + ve;
    #pragma unroll
    for (int j = 0; j < 8; ++j) va[j] = vp[(size_t)j * (Hc * Ec)];
  };
  auto commit = [&](int buf) {
    SW kv;
    kv.u[0] = cvtpk(ka.x, ka.y); kv.u[1] = cvtpk(ka.z, ka.w);
    kv.u[2] = cvtpk(kb.x, kb.y); kv.u[3] = cvtpk(kb.z, kb.w);
    *reinterpret_cast<short8*>(&smem[buf * 4096 + ((srow * 64 + sc8) ^ ((srow & 7) << 3))]) = kv.s8;
    SW vv;
    vv.u[0] = cvtpk(va[0], va[1]); vv.u[1] = cvtpk(va[2], va[3]);
    vv.u[2] = cvtpk(va[4], va[5]); vv.u[3] = cvtpk(va[6], va[7]);
    *reinterpret_cast<short8*>(&smem[8192 + buf * 4096 + ve * 64 + ((w ^ (ve & 7)) << 3)]) = vv.s8;
  };

  const int qmax_w = Qb + qsub * 16 + 15;
  const int nrounds = qblk + 1;

  issue(0);
  commit(0);
  __syncthreads();

  int cur = 0;
  for (int rd = 0; rd < nrounds; ++rd) {
    const int r0 = rd * 64;
    const bool pre = (rd + 1 < nrounds);
    if (pre) issue(r0 + 64);   // global loads overlap compute below

    const int sbase = r0 + par * 32;
    if (sbase <= qmax_w) {
      // ---- QK^T: scores[16 q][32 s] from this parity's half-tile ----
      f32x4 sc[2] = {zero4, zero4};
      #pragma unroll
      for (int c = 0; c < 2; ++c) {
        #pragma unroll
        for (int cb = 0; cb < 2; ++cb) {
          const int row = par * 32 + cb * 16 + n;
          const int idx = cur * 4096 + ((row * 64 + c * 32 + g * 8) ^ ((n & 7) << 3));
          short8 kf = *reinterpret_cast<const short8*>(&smem[idx]);
          sc[cb] = MFMA16(qf[c], kf, sc[cb]);
        }
      }

      // ---- online softmax; C layout: row q16 = g*4+r, col s16 = n ----
      float s_f[2][4];
      const bool domask = (sbase + 31) > (Qb + qsub * 16);
      #pragma unroll
      for (int cb = 0; cb < 2; ++cb) {
        #pragma unroll
        for (int r = 0; r < 4; ++r) {
          float v = sc[cb][r];
          if (domask) {
            const int s = sbase + cb * 16 + n;
            const int q = Qb + qsub * 16 + g * 4 + r;
            if (s > q) v = NEGBIG;
          }
          s_f[cb][r] = v;
        }
      }
      float mx[4];
      #pragma unroll
      for (int r = 0; r < 4; ++r) mx[r] = fmaxf(s_f[0][r], s_f[1][r]);
      #pragma unroll
      for (int r = 0; r < 4; ++r) mx[r] = dppmax<0xB1>(mx[r]);
      #pragma unroll
      for (int r = 0; r < 4; ++r) mx[r] = dppmax<0x4E>(mx[r]);
      #pragma unroll
      for (int r = 0; r < 4; ++r) mx[r] = dppmax<0x141>(mx[r]);
      #pragma unroll
      for (int r = 0; r < 4; ++r) mx[r] = dppmax<0x140>(mx[r]);

      float afac[4];
      #pragma unroll
      for (int r = 0; r < 4; ++r) {
        const float mn = fmaxf(mrun[r], mx[r]);
        afac[r] = exp2f((mrun[r] - mn) * LOG2E);
        mrun[r] = mn;
      }

      // ---- P -> bf16 -> pt (k-chunk swizzled) ----
      #pragma unroll
      for (int cb = 0; cb < 2; ++cb) {
        float p0 = exp2f((s_f[cb][0] - mrun[0]) * LOG2E);
        float p1 = exp2f((s_f[cb][1] - mrun[1]) * LOG2E);
        float p2 = exp2f((s_f[cb][2] - mrun[2]) * LOG2E);
        float p3 = exp2f((s_f[cb][3] - mrun[3]) * LOG2E);
        unsigned u01 = cvtpk(p0, p1);
        unsigned u23 = cvtpk(p2, p3);
        const int slot = (cb * 2 + (n >> 3)) ^ g;   // chunk ^ (q16>>2), writer q16>>2 = g
        const int base = slot * 8 + (n & 7);
        pt[(g * 4 + 0) * 32 + base] = (short)(u01 & 0xffff);
        pt[(g * 4 + 1) * 32 + base] = (short)(u01 >> 16);
        pt[(g * 4 + 2) * 32 + base] = (short)(u23 & 0xffff);
        pt[(g * 4 + 3) * 32 + base] = (short)(u23 >> 16);
      }
      asm volatile("s_waitcnt lgkmcnt(0)" ::: "memory");
      const int rslot = g ^ ((n >> 2) & 3);         // chunk g, reader q16 = n
      short8 pf = *reinterpret_cast<const short8*>(&pt[n * 32 + (rslot << 3)]);

      // row sums via ones-MFMA
      f32x4 rs = MFMA16(pf, onesv, zero4);
      #pragma unroll
      for (int r = 0; r < 4; ++r) lrun[r] = lrun[r] * afac[r] + rs[r];
      #pragma unroll
      for (int e4 = 0; e4 < 4; ++e4) {
        #pragma unroll
        for (int r = 0; r < 4; ++r) acc[e4][r] *= afac[r];
      }

      // ---- PV: B-frag = ds_read_b128 from V^T (this parity's s-chunks) ----
      #pragma unroll
      for (int e4 = 0; e4 < 4; ++e4) {
        const int e = e4 * 16 + n;
        const int slot = (par * 4 + g) ^ (e & 7);
        short8 vf = *reinterpret_cast<const short8*>(
            &smem[8192 + cur * 4096 + e * 64 + (slot << 3)]);
        acc[e4] = MFMA16(pf, vf, acc[e4]);
      }
    }

    if (pre) commit(cur ^ 1);
    __syncthreads();
    cur ^= 1;
  }

  // ---- merge parities via LDS (reuse staging buffers), then store ----
  float* mb = reinterpret_cast<float*>(smem);
  if (par == 1) {
    #pragma unroll
    for (int e4 = 0; e4 < 4; ++e4)
      #pragma unroll
      for (int r = 0; r < 4; ++r)
        mb[(qsub * 16 + g * 4 + r) * 64 + e4 * 16 + n] = acc[e4][r];
    if (n == 0) {
      #pragma unroll
      for (int r = 0; r < 4; ++r) {
        mb[4096 + qsub * 16 + g * 4 + r] = mrun[r];
        mb[4160 + qsub * 16 + g * 4 + r] = lrun[r];
      }
    }
  }
  __syncthreads();
  if (par == 0) {
    #pragma unroll
    for (int r = 0; r < 4; ++r) {
      const int q16 = g * 4 + r;
      const float m1 = mb[4096 + qsub * 16 + q16];
      const float l1 = mb[4160 + qsub * 16 + q16];
      const float mm = fmaxf(mrun[r], m1);
      const float a0 = exp2f((mrun[r] - mm) * LOG2E);
      const float a1 = exp2f((m1 - mm) * LOG2E);
      const float inv = 1.0f / (lrun[r] * a0 + l1 * a1);
      const int q = Qb + qsub * 16 + q16;
      float* op = Og + ((size_t)(b * Lc + q) * Hc + h) * Ec + n;
      #pragma unroll
      for (int e4 = 0; e4 < 4; ++e4)
        op[e4 * 16] = (acc[e4][r] * a0 + mb[(qsub * 16 + q16) * 64 + e4 * 16 + n] * a1) * inv;
    }
  }
}

extern "C" void kernel_launch(void* const* d_in, const int* in_sizes, int n_in,
                              void* d_out, int out_size, void* d_ws, size_t ws_size,
                              hipStream_t stream) {
  const float* Q = (const float*)d_in[0];
  const float* K = (const float*)d_in[1];
  const float* V = (const float*)d_in[2];
  float* O = (float*)d_out;
  dim3 grid(Bc * Hc * (Lc / QBLK));
  attn_fwd<<<grid, dim3(512), 0, stream>>>(Q, K, V, O);
}

// Round 4
// 146.876 us; speedup vs baseline: 2.5449x; 2.5449x over previous
//
#include <hip/hip_runtime.h>
#include <hip/hip_bf16.h>

typedef __attribute__((ext_vector_type(8))) short short8;
typedef __attribute__((ext_vector_type(4))) float f32x4;

#define MFMA16(a, b, c) __builtin_amdgcn_mfma_f32_16x16x32_bf16((a), (b), (c), 0, 0, 0)

constexpr int Bc = 2, Lc = 2048, Hc = 16, Ec = 64;
constexpr int QBLK = 64;
constexpr float SCALE = 0.125f;               // 1/sqrt(64), exact in bf16
constexpr float LOG2E = 1.4426950408889634f;
constexpr float NEGBIG = -3.0e38f;

union SW { short8 s8; unsigned u[4]; float4 f4; };

__device__ __forceinline__ unsigned cvtpk(float lo, float hi) {
  unsigned r;
  asm("v_cvt_pk_bf16_f32 %0, %1, %2" : "=v"(r) : "v"(lo), "v"(hi));
  return r;
}

// 16-lane max reduction step on the VALU pipe (DPP).
template <int CTRL>
__device__ __forceinline__ float dppmax(float x) {
  int xi = __builtin_bit_cast(int, x);
  int yi = __builtin_amdgcn_update_dpp(xi, xi, CTRL, 0xF, 0xF, false);
  return fmaxf(x, __builtin_bit_cast(float, yi));
}

__global__ __launch_bounds__(512, 4)
void attn_fwd(const float* __restrict__ Qg, const float* __restrict__ Kg,
              const float* __restrict__ Vg, float* __restrict__ Og) {
  // smem (shorts):
  //  [0,8192):      kt dbuf: [64 s][64 e] bf16, idx ^ ((row&7)<<3)
  //  [8192,16384):  vt dbuf: [64 e][64 s] bf16, s-chunk slot = chunk ^ (e&7)
  //  [16384,20480): pt per wave [16][32], k-chunk slot = chunk ^ (q16>>2)
  // merge scratch (floats, after final barrier): acc 4096 + m 64 + l 64
  __shared__ __align__(16) short smem[20480];

  const int nqb = Lc / QBLK;                 // 32
  const int bid = blockIdx.x;
  const int qblk = (nqb - 1) - (bid % nqb);  // heavy blocks first
  const int h = (bid / nqb) % Hc;
  const int b = bid / (nqb * Hc);
  const int Qb = qblk * QBLK;

  const int t = threadIdx.x;
  const int w = t >> 6;        // 0..7
  const int qsub = w & 3;      // q sub-block
  const int par = w >> 2;      // s parity (0: rows 0-31 of round, 1: rows 32-63)
  const int l = t & 63;
  const int n = l & 15;
  const int g = l >> 4;

  short* pt = smem + 16384 + w * 512;

  // ---- Q fragments (A-layout: row=n, k=g*8+j), scale folded in ----
  short8 qf[2];
  {
    const int q = Qb + qsub * 16 + n;
    const float* qp = Qg + ((size_t)(b * Lc + q) * Hc + h) * Ec + g * 8;
    SW a0, a1;
    a0.f4 = reinterpret_cast<const float4*>(qp)[0];
    a1.f4 = reinterpret_cast<const float4*>(qp)[1];
    SW b0, b1;
    b0.f4 = reinterpret_cast<const float4*>(qp + 32)[0];
    b1.f4 = reinterpret_cast<const float4*>(qp + 32)[1];
    SW r0, r1;
    r0.u[0] = cvtpk(a0.f4.x * SCALE, a0.f4.y * SCALE);
    r0.u[1] = cvtpk(a0.f4.z * SCALE, a0.f4.w * SCALE);
    r0.u[2] = cvtpk(a1.f4.x * SCALE, a1.f4.y * SCALE);
    r0.u[3] = cvtpk(a1.f4.z * SCALE, a1.f4.w * SCALE);
    r1.u[0] = cvtpk(b0.f4.x * SCALE, b0.f4.y * SCALE);
    r1.u[1] = cvtpk(b0.f4.z * SCALE, b0.f4.w * SCALE);
    r1.u[2] = cvtpk(b1.f4.x * SCALE, b1.f4.y * SCALE);
    r1.u[3] = cvtpk(b1.f4.z * SCALE, b1.f4.w * SCALE);
    qf[0] = r0.s8;
    qf[1] = r1.s8;
  }

  short8 onesv;
  #pragma unroll
  for (int j = 0; j < 8; ++j) onesv[j] = (short)0x3F80;  // bf16 1.0
  const f32x4 zero4 = {0.f, 0.f, 0.f, 0.f};

  f32x4 acc[4] = {zero4, zero4, zero4, zero4};
  float mrun[4] = {NEGBIG, NEGBIG, NEGBIG, NEGBIG};
  float lrun[4] = {0.f, 0.f, 0.f, 0.f};

  // staging coordinates: 512 threads stage 64 rows of K and V^T per round
  const int srow = t >> 3, sc8 = (t & 7) * 8;  // K: row 0..63, 8 cols
  const int ve = l, vs0 = w * 8;               // V^T: col e = lane, 8 s rows

  float4 ka, kb;
  float va[8];

  auto issue = [&](int r0) {
    const float* kp = Kg + ((size_t)(b * Lc + r0 + srow) * Hc + h) * Ec + sc8;
    ka = reinterpret_cast<const float4*>(kp)[0];
    kb = reinterpret_cast<const float4*>(kp)[1];
    const float* vp = Vg + ((size_t)(b * Lc + r0 + vs0) * Hc + h) * Ec + ve;
    #pragma unroll
    for (int j = 0; j < 8; ++j) va[j] = vp[(size_t)j * (Hc * Ec)];
  };
  auto commit = [&](int buf) {
    SW kv;
    kv.u[0] = cvtpk(ka.x, ka.y); kv.u[1] = cvtpk(ka.z, ka.w);
    kv.u[2] = cvtpk(kb.x, kb.y); kv.u[3] = cvtpk(kb.z, kb.w);
    *reinterpret_cast<short8*>(&smem[buf * 4096 + ((srow * 64 + sc8) ^ ((srow & 7) << 3))]) = kv.s8;
    SW vv;
    vv.u[0] = cvtpk(va[0], va[1]); vv.u[1] = cvtpk(va[2], va[3]);
    vv.u[2] = cvtpk(va[4], va[5]); vv.u[3] = cvtpk(va[6], va[7]);
    *reinterpret_cast<short8*>(&smem[8192 + buf * 4096 + ve * 64 + ((w ^ (ve & 7)) << 3)]) = vv.s8;
  };

  const int qmax_w = Qb + qsub * 16 + 15;
  const int nrounds = qblk + 1;

  issue(0);
  commit(0);
  __syncthreads();

  int cur = 0;
  for (int rd = 0; rd < nrounds; ++rd) {
    const int r0 = rd * 64;
    const bool pre = (rd + 1 < nrounds);
    if (pre) issue(r0 + 64);   // global loads overlap compute below

    const int sbase = r0 + par * 32;
    if (sbase <= qmax_w) {
      // ---- QK^T: scores[16 q][32 s] from this parity's half-tile ----
      f32x4 sc[2] = {zero4, zero4};
      #pragma unroll
      for (int c = 0; c < 2; ++c) {
        #pragma unroll
        for (int cb = 0; cb < 2; ++cb) {
          const int row = par * 32 + cb * 16 + n;
          const int idx = cur * 4096 + ((row * 64 + c * 32 + g * 8) ^ ((n & 7) << 3));
          short8 kf = *reinterpret_cast<const short8*>(&smem[idx]);
          sc[cb] = MFMA16(qf[c], kf, sc[cb]);
        }
      }

      // ---- online softmax; C layout: row q16 = g*4+r, col s16 = n ----
      float s_f[2][4];
      const bool domask = (sbase + 31) > (Qb + qsub * 16);
      #pragma unroll
      for (int cb = 0; cb < 2; ++cb) {
        #pragma unroll
        for (int r = 0; r < 4; ++r) {
          float v = sc[cb][r];
          if (domask) {
            const int s = sbase + cb * 16 + n;
            const int q = Qb + qsub * 16 + g * 4 + r;
            if (s > q) v = NEGBIG;
          }
          s_f[cb][r] = v;
        }
      }
      float mx[4];
      #pragma unroll
      for (int r = 0; r < 4; ++r) mx[r] = fmaxf(s_f[0][r], s_f[1][r]);
      #pragma unroll
      for (int r = 0; r < 4; ++r) mx[r] = dppmax<0xB1>(mx[r]);
      #pragma unroll
      for (int r = 0; r < 4; ++r) mx[r] = dppmax<0x4E>(mx[r]);
      #pragma unroll
      for (int r = 0; r < 4; ++r) mx[r] = dppmax<0x141>(mx[r]);
      #pragma unroll
      for (int r = 0; r < 4; ++r) mx[r] = dppmax<0x140>(mx[r]);

      float afac[4];
      #pragma unroll
      for (int r = 0; r < 4; ++r) {
        const float mn = fmaxf(mrun[r], mx[r]);
        afac[r] = exp2f((mrun[r] - mn) * LOG2E);
        mrun[r] = mn;
      }

      // ---- P -> bf16 -> pt (k-chunk swizzled) ----
      #pragma unroll
      for (int cb = 0; cb < 2; ++cb) {
        float p0 = exp2f((s_f[cb][0] - mrun[0]) * LOG2E);
        float p1 = exp2f((s_f[cb][1] - mrun[1]) * LOG2E);
        float p2 = exp2f((s_f[cb][2] - mrun[2]) * LOG2E);
        float p3 = exp2f((s_f[cb][3] - mrun[3]) * LOG2E);
        unsigned u01 = cvtpk(p0, p1);
        unsigned u23 = cvtpk(p2, p3);
        const int slot = (cb * 2 + (n >> 3)) ^ g;   // chunk ^ (q16>>2), writer q16>>2 = g
        const int base = slot * 8 + (n & 7);
        pt[(g * 4 + 0) * 32 + base] = (short)(u01 & 0xffff);
        pt[(g * 4 + 1) * 32 + base] = (short)(u01 >> 16);
        pt[(g * 4 + 2) * 32 + base] = (short)(u23 & 0xffff);
        pt[(g * 4 + 3) * 32 + base] = (short)(u23 >> 16);
      }
      asm volatile("s_waitcnt lgkmcnt(0)" ::: "memory");
      const int rslot = g ^ ((n >> 2) & 3);         // chunk g, reader q16 = n
      short8 pf = *reinterpret_cast<const short8*>(&pt[n * 32 + (rslot << 3)]);

      // row sums via ones-MFMA
      f32x4 rs = MFMA16(pf, onesv, zero4);
      #pragma unroll
      for (int r = 0; r < 4; ++r) lrun[r] = lrun[r] * afac[r] + rs[r];
      #pragma unroll
      for (int e4 = 0; e4 < 4; ++e4) {
        #pragma unroll
        for (int r = 0; r < 4; ++r) acc[e4][r] *= afac[r];
      }

      // ---- PV: B-frag = ds_read_b128 from V^T (this parity's s-chunks) ----
      #pragma unroll
      for (int e4 = 0; e4 < 4; ++e4) {
        const int e = e4 * 16 + n;
        const int slot = (par * 4 + g) ^ (e & 7);
        short8 vf = *reinterpret_cast<const short8*>(
            &smem[8192 + cur * 4096 + e * 64 + (slot << 3)]);
        acc[e4] = MFMA16(pf, vf, acc[e4]);
      }
    }

    if (pre) commit(cur ^ 1);
    __syncthreads();
    cur ^= 1;
  }

  // ---- merge parities via LDS (reuse staging buffers), then store ----
  float* mb = reinterpret_cast<float*>(smem);
  if (par == 1) {
    #pragma unroll
    for (int e4 = 0; e4 < 4; ++e4)
      #pragma unroll
      for (int r = 0; r < 4; ++r)
        mb[(qsub * 16 + g * 4 + r) * 64 + e4 * 16 + n] = acc[e4][r];
    if (n == 0) {
      #pragma unroll
      for (int r = 0; r < 4; ++r) {
        mb[4096 + qsub * 16 + g * 4 + r] = mrun[r];
        mb[4160 + qsub * 16 + g * 4 + r] = lrun[r];
      }
    }
  }
  __syncthreads();
  if (par == 0) {
    #pragma unroll
    for (int r = 0; r < 4; ++r) {
      const int q16 = g * 4 + r;
      const float m1 = mb[4096 + qsub * 16 + q16];
      const float l1 = mb[4160 + qsub * 16 + q16];
      const float mm = fmaxf(mrun[r], m1);
      const float a0 = exp2f((mrun[r] - mm) * LOG2E);
      const float a1 = exp2f((m1 - mm) * LOG2E);
      const float inv = 1.0f / (lrun[r] * a0 + l1 * a1);
      const int q = Qb + qsub * 16 + q16;
      float* op = Og + ((size_t)(b * Lc + q) * Hc + h) * Ec + n;
      #pragma unroll
      for (int e4 = 0; e4 < 4; ++e4)
        op[e4 * 16] = (acc[e4][r] * a0 + mb[(qsub * 16 + q16) * 64 + e4 * 16 + n] * a1) * inv;
    }
  }
}

extern "C" void kernel_launch(void* const* d_in, const int* in_sizes, int n_in,
                              void* d_out, int out_size, void* d_ws, size_t ws_size,
                              hipStream_t stream) {
  const float* Q = (const float*)d_in[0];
  const float* K = (const float*)d_in[1];
  const float* V = (const float*)d_in[2];
  float* O = (float*)d_out;
  dim3 grid(Bc * Hc * (Lc / QBLK));
  attn_fwd<<<grid, dim3(512), 0, stream>>>(Q, K, V, O);
}

// Round 5
// 115.739 us; speedup vs baseline: 3.2296x; 1.2690x over previous
//
#include <hip/hip_runtime.h>
#include <hip/hip_bf16.h>

typedef __attribute__((ext_vector_type(8))) short short8;
typedef __attribute__((ext_vector_type(4))) float f32x4;

#define MFMA16(a, b, c) __builtin_amdgcn_mfma_f32_16x16x32_bf16((a), (b), (c), 0, 0, 0)

constexpr int Bc = 2, Lc = 2048, Hc = 16, Ec = 64;
constexpr int QBLK = 64;
constexpr float SCALE = 0.125f;               // 1/sqrt(64), exact in bf16
constexpr float LOG2E = 1.4426950408889634f;
constexpr float NEGBIG = -3.0e38f;

union SW { short8 s8; unsigned u[4]; float4 f4; };

__device__ __forceinline__ unsigned cvtpk(float lo, float hi) {
  unsigned r;
  asm("v_cvt_pk_bf16_f32 %0, %1, %2" : "=v"(r) : "v"(lo), "v"(hi));
  return r;
}

// 16-lane max reduction step on the VALU pipe (DPP).
template <int CTRL>
__device__ __forceinline__ float dppmax(float x) {
  int xi = __builtin_bit_cast(int, x);
  int yi = __builtin_amdgcn_update_dpp(xi, xi, CTRL, 0xF, 0xF, false);
  return fmaxf(x, __builtin_bit_cast(float, yi));
}

__global__ __launch_bounds__(512, 4)
void attn_fwd(const float* __restrict__ Qg, const float* __restrict__ Kg,
              const float* __restrict__ Vg, float* __restrict__ Og) {
  // smem (shorts):
  //  [0,8192):      kt dbuf: [64 s][64 e] bf16, idx ^ ((row&7)<<3)
  //  [8192,16384):  vt dbuf: [64 e][64 s] bf16, s-chunk slot = chunk ^ (e&7)
  //  [16384,20480): pt per wave [16][32], k-chunk slot = chunk ^ (q16>>2)
  // merge scratch (floats, after final barrier): acc 4096 + m 64 + l 64
  __shared__ __align__(16) short smem[20480];

  // ---- CU-balanced block -> (b,h,qblk) mapping ----
  // CU = f(bid mod 256) under XCD round-robin; the 4 blocks {c, c+256, c+512,
  // c+768} share a CU. Give them qblk = {p, 31-p, (p+16)&31, (15-p)&31}:
  // per-CU round-units = (p+1)+(32-p)+(((p+16)&31)+1)+(32-((p+16)&31)) = 66
  // for every CU -> balanced.
  const int bid = blockIdx.x;
  const int chunk = bid >> 8;       // 0..3
  const int c = bid & 255;
  const int p = c & 31;
  int qblk;
  if (chunk == 0)       qblk = p;
  else if (chunk == 1)  qblk = 31 - p;
  else if (chunk == 2)  qblk = (p + 16) & 31;
  else                  qblk = (15 - p) & 31;
  const int bh = chunk * 8 + (c >> 5);   // 0..63, each (b,h) hit once per qblk
  const int h = bh & (Hc - 1);
  const int b = bh >> 4;
  const int Qb = qblk * QBLK;

  const int t = threadIdx.x;
  const int w = t >> 6;        // 0..7
  const int qsub = w & 3;      // q sub-block
  const int par = w >> 2;      // s parity (0: rows 0-31 of round, 1: rows 32-63)
  const int l = t & 63;
  const int n = l & 15;
  const int g = l >> 4;

  short* pt = smem + 16384 + w * 512;

  // ---- Q fragments (A-layout: row=n, k=g*8+j), scale folded in ----
  short8 qf[2];
  {
    const int q = Qb + qsub * 16 + n;
    const float* qp = Qg + ((size_t)(b * Lc + q) * Hc + h) * Ec + g * 8;
    SW a0, a1;
    a0.f4 = reinterpret_cast<const float4*>(qp)[0];
    a1.f4 = reinterpret_cast<const float4*>(qp)[1];
    SW b0, b1;
    b0.f4 = reinterpret_cast<const float4*>(qp + 32)[0];
    b1.f4 = reinterpret_cast<const float4*>(qp + 32)[1];
    SW r0, r1;
    r0.u[0] = cvtpk(a0.f4.x * SCALE, a0.f4.y * SCALE);
    r0.u[1] = cvtpk(a0.f4.z * SCALE, a0.f4.w * SCALE);
    r0.u[2] = cvtpk(a1.f4.x * SCALE, a1.f4.y * SCALE);
    r0.u[3] = cvtpk(a1.f4.z * SCALE, a1.f4.w * SCALE);
    r1.u[0] = cvtpk(b0.f4.x * SCALE, b0.f4.y * SCALE);
    r1.u[1] = cvtpk(b0.f4.z * SCALE, b0.f4.w * SCALE);
    r1.u[2] = cvtpk(b1.f4.x * SCALE, b1.f4.y * SCALE);
    r1.u[3] = cvtpk(b1.f4.z * SCALE, b1.f4.w * SCALE);
    qf[0] = r0.s8;
    qf[1] = r1.s8;
  }

  short8 onesv;
  #pragma unroll
  for (int j = 0; j < 8; ++j) onesv[j] = (short)0x3F80;  // bf16 1.0
  const f32x4 zero4 = {0.f, 0.f, 0.f, 0.f};

  f32x4 acc[4] = {zero4, zero4, zero4, zero4};
  float mrun[4] = {NEGBIG, NEGBIG, NEGBIG, NEGBIG};
  float lrun[4] = {0.f, 0.f, 0.f, 0.f};

  // staging coordinates: 512 threads stage 64 rows of K and V^T per round
  const int srow = t >> 3, sc8 = (t & 7) * 8;  // K: row 0..63, 8 cols
  const int ve = l, vs0 = w * 8;               // V^T: col e = lane, 8 s rows

  float4 ka, kb;
  float va[8];

  auto issue = [&](int r0) {
    const float* kp = Kg + ((size_t)(b * Lc + r0 + srow) * Hc + h) * Ec + sc8;
    ka = reinterpret_cast<const float4*>(kp)[0];
    kb = reinterpret_cast<const float4*>(kp)[1];
    const float* vp = Vg + ((size_t)(b * Lc + r0 + vs0) * Hc + h) * Ec + ve;
    #pragma unroll
    for (int j = 0; j < 8; ++j) va[j] = vp[(size_t)j * (Hc * Ec)];
  };
  auto commit = [&](int buf) {
    SW kv;
    kv.u[0] = cvtpk(ka.x, ka.y); kv.u[1] = cvtpk(ka.z, ka.w);
    kv.u[2] = cvtpk(kb.x, kb.y); kv.u[3] = cvtpk(kb.z, kb.w);
    *reinterpret_cast<short8*>(&smem[buf * 4096 + ((srow * 64 + sc8) ^ ((srow & 7) << 3))]) = kv.s8;
    SW vv;
    vv.u[0] = cvtpk(va[0], va[1]); vv.u[1] = cvtpk(va[2], va[3]);
    vv.u[2] = cvtpk(va[4], va[5]); vv.u[3] = cvtpk(va[6], va[7]);
    *reinterpret_cast<short8*>(&smem[8192 + buf * 4096 + ve * 64 + ((w ^ (ve & 7)) << 3)]) = vv.s8;
  };

  const int qmax_w = Qb + qsub * 16 + 15;
  const int nrounds = qblk + 1;

  issue(0);
  commit(0);
  __syncthreads();

  int cur = 0;
  for (int rd = 0; rd < nrounds; ++rd) {
    const int r0 = rd * 64;
    const bool pre = (rd + 1 < nrounds);
    if (pre) issue(r0 + 64);   // global loads overlap compute below

    const int sbase = r0 + par * 32;
    if (sbase <= qmax_w) {
      // ---- QK^T: scores[16 q][32 s] from this parity's half-tile ----
      f32x4 sc[2] = {zero4, zero4};
      #pragma unroll
      for (int cc = 0; cc < 2; ++cc) {
        #pragma unroll
        for (int cb = 0; cb < 2; ++cb) {
          const int row = par * 32 + cb * 16 + n;
          const int idx = cur * 4096 + ((row * 64 + cc * 32 + g * 8) ^ ((n & 7) << 3));
          short8 kf = *reinterpret_cast<const short8*>(&smem[idx]);
          sc[cb] = MFMA16(qf[cc], kf, sc[cb]);
        }
      }

      // ---- online softmax; C layout: row q16 = g*4+r, col s16 = n ----
      float s_f[2][4];
      const bool domask = (sbase + 31) > (Qb + qsub * 16);
      #pragma unroll
      for (int cb = 0; cb < 2; ++cb) {
        #pragma unroll
        for (int r = 0; r < 4; ++r) {
          float v = sc[cb][r];
          if (domask) {
            const int s = sbase + cb * 16 + n;
            const int q = Qb + qsub * 16 + g * 4 + r;
            if (s > q) v = NEGBIG;
          }
          s_f[cb][r] = v;
        }
      }
      float mx[4];
      #pragma unroll
      for (int r = 0; r < 4; ++r) mx[r] = fmaxf(s_f[0][r], s_f[1][r]);
      #pragma unroll
      for (int r = 0; r < 4; ++r) mx[r] = dppmax<0xB1>(mx[r]);
      #pragma unroll
      for (int r = 0; r < 4; ++r) mx[r] = dppmax<0x4E>(mx[r]);
      #pragma unroll
      for (int r = 0; r < 4; ++r) mx[r] = dppmax<0x141>(mx[r]);
      #pragma unroll
      for (int r = 0; r < 4; ++r) mx[r] = dppmax<0x140>(mx[r]);

      float afac[4];
      #pragma unroll
      for (int r = 0; r < 4; ++r) {
        const float mn = fmaxf(mrun[r], mx[r]);
        afac[r] = exp2f((mrun[r] - mn) * LOG2E);
        mrun[r] = mn;
      }

      // ---- P -> bf16 -> pt (k-chunk swizzled) ----
      #pragma unroll
      for (int cb = 0; cb < 2; ++cb) {
        float p0 = exp2f((s_f[cb][0] - mrun[0]) * LOG2E);
        float p1 = exp2f((s_f[cb][1] - mrun[1]) * LOG2E);
        float p2 = exp2f((s_f[cb][2] - mrun[2]) * LOG2E);
        float p3 = exp2f((s_f[cb][3] - mrun[3]) * LOG2E);
        unsigned u01 = cvtpk(p0, p1);
        unsigned u23 = cvtpk(p2, p3);
        const int slot = (cb * 2 + (n >> 3)) ^ g;   // chunk ^ (q16>>2), writer q16>>2 = g
        const int base = slot * 8 + (n & 7);
        pt[(g * 4 + 0) * 32 + base] = (short)(u01 & 0xffff);
        pt[(g * 4 + 1) * 32 + base] = (short)(u01 >> 16);
        pt[(g * 4 + 2) * 32 + base] = (short)(u23 & 0xffff);
        pt[(g * 4 + 3) * 32 + base] = (short)(u23 >> 16);
      }
      asm volatile("s_waitcnt lgkmcnt(0)" ::: "memory");
      const int rslot = g ^ ((n >> 2) & 3);         // chunk g, reader q16 = n
      short8 pf = *reinterpret_cast<const short8*>(&pt[n * 32 + (rslot << 3)]);

      // row sums via ones-MFMA
      f32x4 rs = MFMA16(pf, onesv, zero4);
      #pragma unroll
      for (int r = 0; r < 4; ++r) lrun[r] = lrun[r] * afac[r] + rs[r];
      #pragma unroll
      for (int e4 = 0; e4 < 4; ++e4) {
        #pragma unroll
        for (int r = 0; r < 4; ++r) acc[e4][r] *= afac[r];
      }

      // ---- PV: B-frag = ds_read_b128 from V^T (this parity's s-chunks) ----
      #pragma unroll
      for (int e4 = 0; e4 < 4; ++e4) {
        const int e = e4 * 16 + n;
        const int slot = (par * 4 + g) ^ (e & 7);
        short8 vf = *reinterpret_cast<const short8*>(
            &smem[8192 + cur * 4096 + e * 64 + (slot << 3)]);
        acc[e4] = MFMA16(pf, vf, acc[e4]);
      }
    }

    if (pre) commit(cur ^ 1);
    __syncthreads();
    cur ^= 1;
  }

  // ---- merge parities via LDS (reuse staging buffers), then store ----
  float* mb = reinterpret_cast<float*>(smem);
  if (par == 1) {
    #pragma unroll
    for (int e4 = 0; e4 < 4; ++e4)
      #pragma unroll
      for (int r = 0; r < 4; ++r)
        mb[(qsub * 16 + g * 4 + r) * 64 + e4 * 16 + n] = acc[e4][r];
    if (n == 0) {
      #pragma unroll
      for (int r = 0; r < 4; ++r) {
        mb[4096 + qsub * 16 + g * 4 + r] = mrun[r];
        mb[4160 + qsub * 16 + g * 4 + r] = lrun[r];
      }
    }
  }
  __syncthreads();
  if (par == 0) {
    #pragma unroll
    for (int r = 0; r < 4; ++r) {
      const int q16 = g * 4 + r;
      const float m1 = mb[4096 + qsub * 16 + q16];
      const float l1 = mb[4160 + qsub * 16 + q16];
      const float mm = fmaxf(mrun[r], m1);
      const float a0 = exp2f((mrun[r] - mm) * LOG2E);
      const float a1 = exp2f((m1 - mm) * LOG2E);
      const float inv = 1.0f / (lrun[r] * a0 + l1 * a1);
      const int q = Qb + qsub * 16 + q16;
      float* op = Og + ((size_t)(b * Lc + q) * Hc + h) * Ec + n;
      #pragma unroll
      for (int e4 = 0; e4 < 4; ++e4)
        op[e4 * 16] = (acc[e4][r] * a0 + mb[(qsub * 16 + q16) * 64 + e4 * 16 + n] * a1) * inv;
    }
  }
}

extern "C" void kernel_launch(void* const* d_in, const int* in_sizes, int n_in,
                              void* d_out, int out_size, void* d_ws, size_t ws_size,
                              hipStream_t stream) {
  const float* Q = (const float*)d_in[0];
  const float* K = (const float*)d_in[1];
  const float* V = (const float*)d_in[2];
  float* O = (float*)d_out;
  dim3 grid(Bc * Hc * (Lc / QBLK));
  attn_fwd<<<grid, dim3(512), 0, stream>>>(Q, K, V, O);
}